// Round 3
// baseline (224.597 us; speedup 1.0000x reference)
//
#include <hip/hip_runtime.h>
#include <hip/hip_bf16.h>

typedef _Float16 f16x8 __attribute__((ext_vector_type(8)));
typedef _Float16 f16x2 __attribute__((ext_vector_type(2)));
typedef float f32x4 __attribute__((ext_vector_type(4)));
typedef unsigned int u32;
typedef u32 u32x2 __attribute__((ext_vector_type(2)));

#define LOG2E 1.4426950408889634f

// B=16, C=512, HEAD=8, D=64, N=1024 (W=H=32)

__device__ inline void gll16(const void* g, void* l) {
  __builtin_amdgcn_global_load_lds(
      (const __attribute__((address_space(1))) void*)g,
      (__attribute__((address_space(3))) void*)l, 16, 0, 0);
}

// ---------------- prep: Wall f16 + pos f16 (pos pre-scaled by log2e) ----------------
__global__ __launch_bounds__(256) void prep_kernel(
    const float* __restrict__ Wq, const float* __restrict__ Wk, const float* __restrict__ Wv,
    const float* __restrict__ rel_h, const float* __restrict__ rel_w,
    _Float16* __restrict__ Wall, _Float16* __restrict__ post) {
  int idx = blockIdx.x * 256 + threadIdx.x;
  if (idx < 1536 * 512) {
    int o = idx >> 9;
    float wv;
    if (o < 512) wv = Wq[idx];
    else if (o < 1024) wv = Wk[idx - 512 * 512];
    else wv = Wv[idx - 1024 * 512];
    Wall[idx] = (_Float16)wv;
  } else {
    int p = idx - 1536 * 512;            // [0, 8*1024*64)
    int h = p >> 16;
    int rem = p & 65535;
    int n = rem >> 6;
    int d = rem & 63;
    float v = rel_h[(h * 64 + d) * 32 + (n & 31)] + rel_w[(h * 64 + d) * 32 + (n >> 5)];
    post[p] = (_Float16)(v * LOG2E);
  }
}

// ---------------- transpose: x[B,C,N] f32 -> Xt[B*N, C] f16 ----------------
__global__ __launch_bounds__(256) void transpose_kernel(
    const float* __restrict__ x, _Float16* __restrict__ Xt) {
  __shared__ float tl[64][65];
  int bid = blockIdx.x;
  int b = bid >> 7;
  int rem = bid & 127;
  int c0 = (rem >> 4) * 64;
  int n0 = (rem & 15) * 64;
  int t = threadIdx.x;
#pragma unroll
  for (int p = 0; p < 16; ++p) {
    int idx = p * 256 + t;
    int i = idx >> 6, j = idx & 63;
    tl[i][j] = x[((size_t)b * 512 + c0 + i) * 1024 + n0 + j];
  }
  __syncthreads();
#pragma unroll
  for (int p = 0; p < 16; ++p) {
    int idx = p * 256 + t;
    int j = idx >> 6, i = idx & 63;
    Xt[((size_t)b * 1024 + n0 + j) * 512 + c0 + i] = (_Float16)tl[i][j];
  }
}

// ---------------- QKV projection GEMM ----------------
// writes Kext[b][h][n][0:64]=k*log2e, [64:128]=q ; v[b][h][d][n]  (f16)
__global__ __launch_bounds__(256) void qkv_gemm(
    const _Float16* __restrict__ Wall, const _Float16* __restrict__ Xt,
    const float* __restrict__ bq, const float* __restrict__ bk, const float* __restrict__ bv,
    _Float16* __restrict__ kext, _Float16* __restrict__ vv) {
  __shared__ _Float16 At[128 * 64];
  __shared__ _Float16 Bt[128 * 64];
  int bid = blockIdx.x;
  int mb = bid >> 7, nb = bid & 127;
  int o0 = mb * 128, j0 = nb * 128;
  int t = threadIdx.x;
  int w = t >> 6, l = t & 63, lg = l >> 4, lc = l & 15;
  int wm = w >> 1, wn = w & 1;
  f32x4 acc[4][4];
#pragma unroll
  for (int a = 0; a < 4; ++a)
#pragma unroll
    for (int bb = 0; bb < 4; ++bb) acc[a][bb] = (f32x4){0.f, 0.f, 0.f, 0.f};

  for (int k0 = 0; k0 < 512; k0 += 64) {
    __syncthreads();
#pragma unroll
    for (int p = 0; p < 4; ++p) {
      int li = p * 256 + t;            // 16B chunk index
      int row = li >> 3;               // tile row
      int colb = (li & 7) << 4;        // linear byte col in row
      int scol = (colb ^ ((row & 7) << 4)) >> 1;  // inverse-swizzled f16 col
      gll16(Wall + (size_t)(o0 + row) * 512 + k0 + scol, At + (size_t)li * 8);
      gll16(Xt + (size_t)(j0 + row) * 512 + k0 + scol, Bt + (size_t)li * 8);
    }
    __syncthreads();
#pragma unroll
    for (int kf = 0; kf < 2; ++kf) {
      int kbyte = kf * 64 + lg * 16;
      f16x8 af[4], bf[4];
#pragma unroll
      for (int mi = 0; mi < 4; ++mi) {
        int row = wm * 64 + mi * 16 + lc;
        af[mi] = *(const f16x8*)((const char*)At + row * 128 + (kbyte ^ ((row & 7) << 4)));
      }
#pragma unroll
      for (int ni = 0; ni < 4; ++ni) {
        int row = wn * 64 + ni * 16 + lc;
        bf[ni] = *(const f16x8*)((const char*)Bt + row * 128 + (kbyte ^ ((row & 7) << 4)));
      }
#pragma unroll
      for (int mi = 0; mi < 4; ++mi)
#pragma unroll
        for (int ni = 0; ni < 4; ++ni)
          acc[mi][ni] = __builtin_amdgcn_mfma_f32_16x16x32_f16(af[mi], bf[ni], acc[mi][ni], 0, 0, 0);
    }
  }

  int mode = mb >> 2;  // 0=q, 1=k, 2=v
  const float* bias = (mode == 0) ? bq : ((mode == 1) ? bk : bv);
#pragma unroll
  for (int mi = 0; mi < 4; ++mi) {
    int obase = o0 + wm * 64 + mi * 16 + 4 * lg - mode * 512;
#pragma unroll
    for (int ni = 0; ni < 4; ++ni) {
      int j = j0 + wn * 64 + ni * 16 + lc;
      int b = j >> 10, n = j & 1023;
#pragma unroll
      for (int r = 0; r < 4; ++r) {
        int op = obase + r;                 // channel within matrix [0,512)
        float y = acc[mi][ni][r] + bias[op];
        if (mode == 1) y *= LOG2E;          // fold exp2 base change into k
        int h = op >> 6, d = op & 63;
        if (mode < 2) {
          size_t off = ((((size_t)b * 8 + h) * 1024 + n) * 128) + d + (mode == 0 ? 64 : 0);
          kext[off] = (_Float16)y;
        } else {
          vv[(((size_t)b * 8 + h) * 64 + d) * 1024 + n] = (_Float16)y;
        }
      }
    }
  }
}

// ---------------- fused flash attention + residual ----------------
// Swapped-operand flash attn: S = mfma(Kext, Aext) -> lane owns q-row = lc.
__global__ __launch_bounds__(256, 3) void attn_kernel(
    const _Float16* __restrict__ kext, const _Float16* __restrict__ vv,
    const _Float16* __restrict__ post,
    const float* __restrict__ x, float* __restrict__ out) {
  __shared__ _Float16 Ke[2][8192];   // 64 x 128 f16, rows 256B, XOR-swizzled 16B chunks
  __shared__ _Float16 Pl[4][2048];   // per-wave 32 x 64 f16, rows 128B, XOR-swizzled
  int bid = blockIdx.x;
  int bh = bid & 127, qb = bid >> 7;   // same-bh blocks share XCD (bid%8 == bh%8)
  int b = bh >> 3, h = bh & 7;
  int t = threadIdx.x, w = t >> 6, l = t & 63, lg = l >> 4, lc = l & 15;
  const _Float16* keg = kext + (size_t)bh * (1024 * 128);
  const _Float16* vbh = vv + (size_t)bh * 65536;
  const _Float16* ph = post + (size_t)h * 65536;
  int n0w = qb * 128 + w * 32;

  // A-ext frags (q | pos*log2e), kept in regs all kernel
  f16x8 aq[2][4];
#pragma unroll
  for (int rf = 0; rf < 2; ++rf)
#pragma unroll
    for (int kf = 0; kf < 4; ++kf) {
      int kk = kf * 32 + lg * 8;
      int n = n0w + rf * 16 + lc;
      const _Float16* src = (kf < 2) ? (keg + (size_t)n * 128 + 64 + kk)
                                     : (ph + (size_t)n * 64 + (kk - 64));
      aq[rf][kf] = *(const f16x8*)src;
    }

  float m_r[2], l_r[2];
  f32x4 oacc[2][4];
#pragma unroll
  for (int rf = 0; rf < 2; ++rf) {
    m_r[rf] = -1e30f; l_r[rf] = 0.f;
#pragma unroll
    for (int dt = 0; dt < 4; ++dt) oacc[rf][dt] = (f32x4){0.f, 0.f, 0.f, 0.f};
  }

  auto stage = [&](int buf, int mt) {
    int m0 = mt * 64;
#pragma unroll
    for (int p = 0; p < 4; ++p) {
      int li = p * 256 + t;
      int r = li >> 4, c = li & 15;
      int sc = c ^ (r & 7);
      gll16(keg + (size_t)(m0 + r) * 128 + sc * 8, (char*)Ke[buf] + li * 16);
    }
  };

  stage(0, 0);
  __syncthreads();
  int buf = 0;
  char* pw = (char*)Pl[w];
  int swz = (lc & 7) << 4;

  for (int mt = 0; mt < 16; ++mt) {
    int m0 = mt * 64;
    // V fragments direct from global (L2-resident), issued early to hide latency
    f16x8 bvv[2][4];
#pragma unroll
    for (int ks = 0; ks < 2; ++ks)
#pragma unroll
      for (int dt = 0; dt < 4; ++dt)
        bvv[ks][dt] = *(const f16x8*)(vbh + (size_t)(dt * 16 + lc) * 1024 + m0 + ks * 32 + lg * 8);
    if (mt + 1 < 16) stage(buf ^ 1, mt + 1);
    const char* keb = (const char*)Ke[buf];

    // QK^T-ext, swapped: sS[rf][ms] = C[m_local = 4lg+r, q = lc]
    f32x4 sS[2][4];
#pragma unroll
    for (int rf = 0; rf < 2; ++rf)
#pragma unroll
      for (int ms = 0; ms < 4; ++ms) sS[rf][ms] = (f32x4){0.f, 0.f, 0.f, 0.f};
    __builtin_amdgcn_s_setprio(1);
#pragma unroll
    for (int ms = 0; ms < 4; ++ms) {
      int mr = ms * 16 + lc;
      const char* rowp = keb + mr * 256;
      f16x8 bkf[4];
#pragma unroll
      for (int kf = 0; kf < 4; ++kf) {
        int ch = (kf * 4 + lg) ^ (mr & 7);
        bkf[kf] = *(const f16x8*)(rowp + (ch << 4));
      }
#pragma unroll
      for (int rf = 0; rf < 2; ++rf)
#pragma unroll
        for (int kf = 0; kf < 4; ++kf)
          sS[rf][ms] = __builtin_amdgcn_mfma_f32_16x16x32_f16(bkf[kf], aq[rf][kf], sS[rf][ms], 0, 0, 0);
    }
    __builtin_amdgcn_s_setprio(0);

    // online softmax: stats per-lane (q = lc); logits already in log2 domain
#pragma unroll
    for (int rf = 0; rf < 2; ++rf) {
      float mx = sS[rf][0][0];
#pragma unroll
      for (int ms = 0; ms < 4; ++ms)
#pragma unroll
        for (int r = 0; r < 4; ++r) mx = fmaxf(mx, sS[rf][ms][r]);
      mx = fmaxf(mx, __shfl_xor(mx, 16));
      mx = fmaxf(mx, __shfl_xor(mx, 32));
      float mnew = fmaxf(m_r[rf], mx);
      float scl = exp2f(m_r[rf] - mnew);
      m_r[rf] = mnew;
      float rsum = 0.f;
      char* pb = pw + (rf * 16 + lc) * 128;
#pragma unroll
      for (int ms = 0; ms < 4; ++ms) {
        float p0 = exp2f(sS[rf][ms][0] - mnew);
        float p1 = exp2f(sS[rf][ms][1] - mnew);
        float p2 = exp2f(sS[rf][ms][2] - mnew);
        float p3 = exp2f(sS[rf][ms][3] - mnew);
        rsum += (p0 + p1) + (p2 + p3);
        u32 lo = __builtin_bit_cast(u32, __builtin_amdgcn_cvt_pkrtz(p0, p1));
        u32 hi = __builtin_bit_cast(u32, __builtin_amdgcn_cvt_pkrtz(p2, p3));
        *(u32x2*)(pb + ((ms * 32 + 8 * lg) ^ swz)) = (u32x2){lo, hi};
      }
      rsum += __shfl_xor(rsum, 16);
      rsum += __shfl_xor(rsum, 32);
      l_r[rf] = l_r[rf] * scl + rsum;
#pragma unroll
      for (int dt = 0; dt < 4; ++dt)
#pragma unroll
        for (int r = 0; r < 4; ++r) oacc[rf][dt][r] *= scl;
    }

    // PV swapped: oacc = mfma(V_frag, P_frag) -> C[d = 4lg+r, q = lc]
    __builtin_amdgcn_s_setprio(1);
#pragma unroll
    for (int rf = 0; rf < 2; ++rf) {
      const char* pb = pw + (rf * 16 + lc) * 128;
#pragma unroll
      for (int ks = 0; ks < 2; ++ks) {
        f16x8 pa = *(const f16x8*)(pb + ((ks * 64 + lg * 16) ^ swz));
#pragma unroll
        for (int dt = 0; dt < 4; ++dt)
          oacc[rf][dt] = __builtin_amdgcn_mfma_f32_16x16x32_f16(bvv[ks][dt], pa, oacc[rf][dt], 0, 0, 0);
      }
    }
    __builtin_amdgcn_s_setprio(0);
    __syncthreads();  // Ke dbuf rotate (also drains next-tile gll loads)
    buf ^= 1;
  }

  // epilogue: lane holds d = dt*16+4lg+r, q = n0w+rf*16+lc; stats aligned per-lane
#pragma unroll
  for (int rf = 0; rf < 2; ++rf) {
    float inv = 1.0f / l_r[rf];
    int n = n0w + rf * 16 + lc;
#pragma unroll
    for (int dt = 0; dt < 4; ++dt)
#pragma unroll
      for (int r = 0; r < 4; ++r) {
        int c = h * 64 + dt * 16 + 4 * lg + r;
        size_t off = ((size_t)b * 512 + c) * 1024 + n;
        out[off] = oacc[rf][dt][r] * inv + x[off];
      }
  }
}

extern "C" void kernel_launch(void* const* d_in, const int* in_sizes, int n_in,
                              void* d_out, int out_size, void* d_ws, size_t ws_size,
                              hipStream_t stream) {
  (void)in_sizes; (void)n_in; (void)out_size; (void)ws_size;
  const float* x = (const float*)d_in[0];
  const float* Wq = (const float*)d_in[1];
  const float* bq = (const float*)d_in[2];
  const float* Wk = (const float*)d_in[3];
  const float* bk = (const float*)d_in[4];
  const float* Wv = (const float*)d_in[5];
  const float* bv = (const float*)d_in[6];
  const float* rel_h = (const float*)d_in[7];
  const float* rel_w = (const float*)d_in[8];
  float* out = (float*)d_out;

  char* ws = (char*)d_ws;
  _Float16* Xt   = (_Float16*)(ws);                          // 16 MiB
  _Float16* Wall = (_Float16*)(ws + (16u << 20));            // 1.5 MiB
  _Float16* post = (_Float16*)(ws + (18u << 20));            // 1 MiB
  _Float16* Kext = (_Float16*)(ws + (19u << 20));            // 32 MiB
  _Float16* vw   = (_Float16*)(ws + (51u << 20));            // 16 MiB

  hipLaunchKernelGGL(prep_kernel, dim3(5120), dim3(256), 0, stream,
                     Wq, Wk, Wv, rel_h, rel_w, Wall, post);
  hipLaunchKernelGGL(transpose_kernel, dim3(2048), dim3(256), 0, stream, x, Xt);
  hipLaunchKernelGGL(qkv_gemm, dim3(1536), dim3(256), 0, stream,
                     Wall, Xt, bq, bk, bv, Kext, vw);
  hipLaunchKernelGGL(attn_kernel, dim3(1024), dim3(256), 0, stream,
                     Kext, vw, post, x, out);
}